// Round 7
// baseline (44.647 us; speedup 1.0000x reference)
//
#include <hip/hip_runtime.h>
#include <hip/hip_bf16.h>

typedef __attribute__((ext_vector_type(8))) short bf16x8;
typedef __attribute__((ext_vector_type(8))) unsigned short u16x8;
typedef __attribute__((ext_vector_type(4))) float f32x4;

#define DDIM 1024
#define BM 256
#define BN 128
#define BK 64   // 16 K-steps

__device__ __forceinline__ void gload_lds16(const void* g, void* l) {
  __builtin_amdgcn_global_load_lds((const __attribute__((address_space(1))) void*)g,
                                   (__attribute__((address_space(3))) void*)l,
                                   16, 0, 0);
}

__device__ __forceinline__ unsigned short f2bf(float f) {
  unsigned int u = __float_as_uint(f);
  unsigned int r = (u + 0x7FFFu + ((u >> 16) & 1u)) >> 16;   // RNE
  return (unsigned short)r;
}

// Convert f32 rows -> bf16 rows into workspace.
__global__ __launch_bounds__(256) void s6_convert(
    const float* __restrict__ X, const float* __restrict__ W1,
    const float* __restrict__ W2, const float* __restrict__ W3,
    unsigned short* __restrict__ Xbf, unsigned short* __restrict__ W1bf,
    unsigned short* __restrict__ W2bf, unsigned short* __restrict__ W3bf)
{
  const int wid = threadIdx.x >> 6, lane = threadIdx.x & 63;
  const int row = blockIdx.x * 4 + wid;
  const float* src;
  unsigned short* dst;
  if (row < 8192)      { src = X  + (size_t)row * DDIM;        dst = Xbf  + (size_t)row * DDIM; }
  else if (row < 9216) { int r = row - 8192; src = W1 + (size_t)r * DDIM; dst = W1bf + (size_t)r * DDIM; }
  else if (row < 9232) { int r = row - 9216; src = W2 + (size_t)r * DDIM; dst = W2bf + (size_t)r * DDIM; }
  else                 { int r = row - 9232; src = W3 + (size_t)r * DDIM; dst = W3bf + (size_t)r * DDIM; }

  const float4* s4 = reinterpret_cast<const float4*>(src + lane * 16);
  unsigned short u[16];
  #pragma unroll
  for (int j = 0; j < 4; ++j) {
    float4 v = s4[j];
    u[j*4+0] = f2bf(v.x); u[j*4+1] = f2bf(v.y);
    u[j*4+2] = f2bf(v.z); u[j*4+3] = f2bf(v.w);
  }
  u16x8* d8 = reinterpret_cast<u16x8*>(dst + lane * 16);
  u16x8 lo, hi;
  #pragma unroll
  for (int j = 0; j < 8; ++j) { lo[j] = u[j]; hi[j] = u[j + 8]; }
  d8[0] = lo; d8[1] = hi;
}

// Fused GEMM + projections + softplus epilogue, 8-phase schedule (T3+T4+T5).
// 8 waves (4M x 2N), 256x128 tile, BK=64, 1 block/CU.
__global__ __launch_bounds__(512, 2) void s6_main_fused(
    const unsigned short* __restrict__ Xbf,
    const unsigned short* __restrict__ W1bf,
    const unsigned short* __restrict__ W2bf,
    const unsigned short* __restrict__ W3bf,
    const float* __restrict__ b1,
    const float* __restrict__ b2,
    const float* __restrict__ b3,
    float* __restrict__ Y)
{
  // A: [2][256*64]  B+: [2][192*64] (rows 0-127 W1; 128-143 W2; 144-159 W3; rest pad)
  __shared__ __align__(16) unsigned short lds[2 * 16384 + 2 * 12288];   // 112 KiB
  unsigned short* AB = lds;
  unsigned short* BB = lds + 2 * 16384;

  const int tid  = threadIdx.x;
  const int wid  = tid >> 6;
  const int lane = tid & 63;
  const int tile = (blockIdx.x & 7) * 32 + (blockIdx.x >> 3);   // XCD-chunked
  const int rb   = tile >> 3;
  const int cb   = tile & 7;
  const int row0 = rb * BM;
  const int col0 = cb * BN;
  const int wr = wid >> 1, wc = wid & 1;

  const f32x4 z4 = {0.f, 0.f, 0.f, 0.f};
  f32x4 acc[4][4];
  #pragma unroll
  for (int i = 0; i < 4; ++i)
    #pragma unroll
    for (int j = 0; j < 4; ++j)
      acc[i][j] = z4;
  f32x4 accS[4] = {z4, z4, z4, z4};

  // staging geometry (chunk-XOR pre-swizzled source, linear LDS dest)
  const int srow = tid >> 3;
  const int sdch = (lane & 7) ^ (lane >> 3);
  const unsigned short* gaBase = Xbf  + (size_t)(row0 + srow) * DDIM + sdch * 8;
  const unsigned short* gbBase = W1bf + (size_t)(col0 + srow) * DDIM + sdch * 8;
  const int sub = srow;
  const unsigned short* gwsrc;
  if (sub < 16)      gwsrc = W2bf + (size_t)sub * DDIM;
  else if (sub < 32) gwsrc = W3bf + (size_t)(sub - 16) * DDIM;
  else               gwsrc = W2bf + (size_t)(sub & 15) * DDIM;
  const unsigned short* gwBase = gwsrc + sdch * 8;

  const int fr = lane & 15;
  const int swz0 = (((lane >> 4) + 0) ^ (fr & 7)) * 8;
  const int swz1 = (((lane >> 4) + 4) ^ (fr & 7)) * 8;

#define SA(BUF, KEL, SEG) gload_lds16(gaBase + (KEL) + (SEG) * 64 * DDIM,      \
                                      AB + (BUF) * 16384 + wid * 512 + (SEG) * 4096)
#define SB(BUF, KEL, SEG) gload_lds16(gbBase + (KEL) + (SEG) * 64 * DDIM,      \
                                      BB + (BUF) * 12288 + wid * 512 + (SEG) * 4096)
#define SW(BUF, KEL)      gload_lds16(gwBase + (KEL),                          \
                                      BB + (BUF) * 12288 + wid * 512 + 8192)
#define RA(M, SWZ) (*reinterpret_cast<const bf16x8*>(&Al[(wr * 64 + (M) * 16 + fr) * BK + (SWZ)]))
#define RB(N, SWZ) (*reinterpret_cast<const bf16x8*>(&Bl[(wc * 64 + (N) * 16 + fr) * BK + (SWZ)]))
#define RW(SWZ)    (*reinterpret_cast<const bf16x8*>(&Bl[(128 + wc * 16 + fr) * BK + (SWZ)]))
#define BAR()   __builtin_amdgcn_s_barrier()
#define SCB()   __builtin_amdgcn_sched_barrier(0)
#define LGKM0() asm volatile("s_waitcnt lgkmcnt(0)" ::: "memory")

  // prologue: stage step-0 fully
  SA(0, 0, 0); SA(0, 0, 1); SA(0, 0, 2); SA(0, 0, 3);
  SB(0, 0, 0); SB(0, 0, 1); SW(0, 0);
  asm volatile("s_waitcnt vmcnt(0)" ::: "memory");
  BAR(); SCB();

  for (int t = 0; t < 16; ++t) {
    const int par = t & 1;
    const int nb  = par ^ 1;
    const int kn  = (t + 1) * BK;
    const unsigned short* Al = AB + par * 16384;
    const unsigned short* Bl = BB + par * 12288;
    bf16x8 a0, a1, a2, a3, f0, f1, f2, f3, wf;

    // ---- P0: stage A01(next); vmcnt(2); bar; read ks0 set; 8 MFMA ----
    if (t < 15) {
      SA(nb, kn, 0); SA(nb, kn, 1);
      asm volatile("s_waitcnt vmcnt(2)" ::: "memory");
    } else {
      asm volatile("s_waitcnt vmcnt(0)" ::: "memory");
    }
    BAR(); SCB();
    a0 = RA(0, swz0); a1 = RA(1, swz0);
    f0 = RB(0, swz0); f1 = RB(1, swz0); f2 = RB(2, swz0); f3 = RB(3, swz0);
    wf = RW(swz0);
    LGKM0(); SCB();
    __builtin_amdgcn_s_setprio(1);
    acc[0][0] = __builtin_amdgcn_mfma_f32_16x16x32_bf16(a0, f0, acc[0][0], 0, 0, 0);
    acc[0][1] = __builtin_amdgcn_mfma_f32_16x16x32_bf16(a0, f1, acc[0][1], 0, 0, 0);
    acc[0][2] = __builtin_amdgcn_mfma_f32_16x16x32_bf16(a0, f2, acc[0][2], 0, 0, 0);
    acc[0][3] = __builtin_amdgcn_mfma_f32_16x16x32_bf16(a0, f3, acc[0][3], 0, 0, 0);
    acc[1][0] = __builtin_amdgcn_mfma_f32_16x16x32_bf16(a1, f0, acc[1][0], 0, 0, 0);
    acc[1][1] = __builtin_amdgcn_mfma_f32_16x16x32_bf16(a1, f1, acc[1][1], 0, 0, 0);
    acc[1][2] = __builtin_amdgcn_mfma_f32_16x16x32_bf16(a1, f2, acc[1][2], 0, 0, 0);
    acc[1][3] = __builtin_amdgcn_mfma_f32_16x16x32_bf16(a1, f3, acc[1][3], 0, 0, 0);
    __builtin_amdgcn_s_setprio(0);
    BAR(); SCB();

    // ---- P1: read af23 ks0; stage A23(next); 8 MFMA + 4 proj ----
    a2 = RA(2, swz0); a3 = RA(3, swz0);
    if (t < 15) { SA(nb, kn, 2); SA(nb, kn, 3); }
    BAR(); SCB();
    LGKM0(); SCB();
    __builtin_amdgcn_s_setprio(1);
    acc[2][0] = __builtin_amdgcn_mfma_f32_16x16x32_bf16(a2, f0, acc[2][0], 0, 0, 0);
    acc[2][1] = __builtin_amdgcn_mfma_f32_16x16x32_bf16(a2, f1, acc[2][1], 0, 0, 0);
    acc[2][2] = __builtin_amdgcn_mfma_f32_16x16x32_bf16(a2, f2, acc[2][2], 0, 0, 0);
    acc[2][3] = __builtin_amdgcn_mfma_f32_16x16x32_bf16(a2, f3, acc[2][3], 0, 0, 0);
    acc[3][0] = __builtin_amdgcn_mfma_f32_16x16x32_bf16(a3, f0, acc[3][0], 0, 0, 0);
    acc[3][1] = __builtin_amdgcn_mfma_f32_16x16x32_bf16(a3, f1, acc[3][1], 0, 0, 0);
    acc[3][2] = __builtin_amdgcn_mfma_f32_16x16x32_bf16(a3, f2, acc[3][2], 0, 0, 0);
    acc[3][3] = __builtin_amdgcn_mfma_f32_16x16x32_bf16(a3, f3, acc[3][3], 0, 0, 0);
    accS[0]   = __builtin_amdgcn_mfma_f32_16x16x32_bf16(a0, wf, accS[0], 0, 0, 0);
    accS[1]   = __builtin_amdgcn_mfma_f32_16x16x32_bf16(a1, wf, accS[1], 0, 0, 0);
    accS[2]   = __builtin_amdgcn_mfma_f32_16x16x32_bf16(a2, wf, accS[2], 0, 0, 0);
    accS[3]   = __builtin_amdgcn_mfma_f32_16x16x32_bf16(a3, wf, accS[3], 0, 0, 0);
    __builtin_amdgcn_s_setprio(0);
    BAR(); SCB();

    // ---- P2: read ks1 set; stage B01(next); 8 MFMA ----
    a0 = RA(0, swz1); a1 = RA(1, swz1);
    f0 = RB(0, swz1); f1 = RB(1, swz1); f2 = RB(2, swz1); f3 = RB(3, swz1);
    wf = RW(swz1);
    if (t < 15) { SB(nb, kn, 0); SB(nb, kn, 1); }
    BAR(); SCB();
    LGKM0(); SCB();
    __builtin_amdgcn_s_setprio(1);
    acc[0][0] = __builtin_amdgcn_mfma_f32_16x16x32_bf16(a0, f0, acc[0][0], 0, 0, 0);
    acc[0][1] = __builtin_amdgcn_mfma_f32_16x16x32_bf16(a0, f1, acc[0][1], 0, 0, 0);
    acc[0][2] = __builtin_amdgcn_mfma_f32_16x16x32_bf16(a0, f2, acc[0][2], 0, 0, 0);
    acc[0][3] = __builtin_amdgcn_mfma_f32_16x16x32_bf16(a0, f3, acc[0][3], 0, 0, 0);
    acc[1][0] = __builtin_amdgcn_mfma_f32_16x16x32_bf16(a1, f0, acc[1][0], 0, 0, 0);
    acc[1][1] = __builtin_amdgcn_mfma_f32_16x16x32_bf16(a1, f1, acc[1][1], 0, 0, 0);
    acc[1][2] = __builtin_amdgcn_mfma_f32_16x16x32_bf16(a1, f2, acc[1][2], 0, 0, 0);
    acc[1][3] = __builtin_amdgcn_mfma_f32_16x16x32_bf16(a1, f3, acc[1][3], 0, 0, 0);
    __builtin_amdgcn_s_setprio(0);
    BAR(); SCB();

    // ---- P3: read af23 ks1; stage W(next); 8 MFMA + 4 proj ----
    a2 = RA(2, swz1); a3 = RA(3, swz1);
    if (t < 15) { SW(nb, kn); }
    BAR(); SCB();
    LGKM0(); SCB();
    __builtin_amdgcn_s_setprio(1);
    acc[2][0] = __builtin_amdgcn_mfma_f32_16x16x32_bf16(a2, f0, acc[2][0], 0, 0, 0);
    acc[2][1] = __builtin_amdgcn_mfma_f32_16x16x32_bf16(a2, f1, acc[2][1], 0, 0, 0);
    acc[2][2] = __builtin_amdgcn_mfma_f32_16x16x32_bf16(a2, f2, acc[2][2], 0, 0, 0);
    acc[2][3] = __builtin_amdgcn_mfma_f32_16x16x32_bf16(a2, f3, acc[2][3], 0, 0, 0);
    acc[3][0] = __builtin_amdgcn_mfma_f32_16x16x32_bf16(a3, f0, acc[3][0], 0, 0, 0);
    acc[3][1] = __builtin_amdgcn_mfma_f32_16x16x32_bf16(a3, f1, acc[3][1], 0, 0, 0);
    acc[3][2] = __builtin_amdgcn_mfma_f32_16x16x32_bf16(a3, f2, acc[3][2], 0, 0, 0);
    acc[3][3] = __builtin_amdgcn_mfma_f32_16x16x32_bf16(a3, f3, acc[3][3], 0, 0, 0);
    accS[0]   = __builtin_amdgcn_mfma_f32_16x16x32_bf16(a0, wf, accS[0], 0, 0, 0);
    accS[1]   = __builtin_amdgcn_mfma_f32_16x16x32_bf16(a1, wf, accS[1], 0, 0, 0);
    accS[2]   = __builtin_amdgcn_mfma_f32_16x16x32_bf16(a2, wf, accS[2], 0, 0, 0);
    accS[3]   = __builtin_amdgcn_mfma_f32_16x16x32_bf16(a3, wf, accS[3], 0, 0, 0);
    __builtin_amdgcn_s_setprio(0);
    BAR(); SCB();
  }
#undef SA
#undef SB
#undef SW
#undef RA
#undef RB
#undef RW

  // ---- s[r]: cross-wave exchange (pad 17 = conflict-free) ----
  float* sEx = (float*)lds;           // [2][256][17] f32 = 68 KiB < 112 KiB
  const int n_  = lane & 15;
  const int rgp = (lane >> 4) * 4;
  const float bSelf = (wc == 0 ? b2[n_] : b3[n_]);
  #pragma unroll
  for (int m = 0; m < 4; ++m)
    #pragma unroll
    for (int q = 0; q < 4; ++q)
      sEx[(wc * 256 + wr * 64 + m * 16 + rgp + q) * 17 + n_] = accS[m][q] + bSelf;
  __syncthreads();

  float sv[4][4];
  #pragma unroll
  for (int m = 0; m < 4; ++m) {
    #pragma unroll
    for (int q = 0; q < 4; ++q) {
      const float other = sEx[((wc ^ 1) * 256 + wr * 64 + m * 16 + rgp + q) * 17 + n_];
      float p = (accS[m][q] + bSelf) * other;
      p += __shfl_xor(p, 1, 64);
      p += __shfl_xor(p, 2, 64);
      p += __shfl_xor(p, 4, 64);
      p += __shfl_xor(p, 8, 64);
      sv[m][q] = p;
    }
  }

  // ---- epilogue ----
  #pragma unroll
  for (int m = 0; m < 4; ++m) {
    #pragma unroll
    for (int q = 0; q < 4; ++q) {
      const int gr = row0 + wr * 64 + m * 16 + rgp + q;
      const float svv = sv[m][q];
      const size_t rbase = (size_t)gr * DDIM;
      #pragma unroll
      for (int n = 0; n < 4; ++n) {
        const int gc = col0 + wc * 64 + n * 16 + fr;
        const float z  = acc[m][n][q] + b1[gc];
        const float sp = fmaxf(z, 0.f) + __logf(1.f + __expf(-fabsf(z)));  // softplus
        const float xv = __bfloat162float(*(const __hip_bfloat16*)&Xbf[rbase + gc]);
        Y[rbase + gc] = xv * svv * sp;
      }
    }
  }
}

extern "C" void kernel_launch(void* const* d_in, const int* in_sizes, int n_in,
                              void* d_out, int out_size, void* d_ws, size_t ws_size,
                              hipStream_t stream) {
  const float* x  = (const float*)d_in[0];
  const float* W1 = (const float*)d_in[1];
  const float* b1 = (const float*)d_in[2];
  const float* W2 = (const float*)d_in[3];
  const float* b2 = (const float*)d_in[4];
  const float* W3 = (const float*)d_in[5];
  const float* b3 = (const float*)d_in[6];
  // d_in[7] = A is provably unused (h is zero-initialized in the reference).

  char* ws = (char*)d_ws;
  unsigned short* Xbf  = (unsigned short*)(ws);                          // 16,777,216 B
  unsigned short* W1bf = (unsigned short*)(ws + 16777216);               //  2,097,152 B
  unsigned short* W2bf = (unsigned short*)(ws + 16777216 + 2097152);     //     32,768 B
  unsigned short* W3bf = (unsigned short*)(ws + 16777216 + 2097152 + 32768);

  s6_convert<<<2312, 256, 0, stream>>>(x, W1, W2, W3, Xbf, W1bf, W2bf, W3bf);
  s6_main_fused<<<256, 512, 0, stream>>>(Xbf, W1bf, W2bf, W3bf, b1, b2, b3,
                                         (float*)d_out);
}